// Round 10
// baseline (538.437 us; speedup 1.0000x reference)
//
#include <hip/hip_runtime.h>
#include <cstdint>

#define NN  50000
#define MD  64
#define HD  128
#define RR  4
#define FD  7
#define EE  800000
#define BG  32
#define NMX 512

// MSD bucket sort geometry
#define NH   196
#define NBL  196
#define BE   4096
#define NS   (NH * NBL)
#define NSB  ((NS + 255) / 256)

// pass-split gather geometry
#define NPASS 4
#define GNBP  ((NN + 3) / 4)     // 12500 blocks per pass, 4 nodes (waves) each

typedef __attribute__((ext_vector_type(8))) short bf16x8;
typedef __attribute__((ext_vector_type(4))) float f32x4;
typedef __attribute__((ext_vector_type(4))) unsigned u32x4;

__device__ __forceinline__ unsigned short f2bf(float f) {
    unsigned u = __builtin_bit_cast(unsigned, f);
    u = (u + 0x7fffu + ((u >> 16) & 1u)) >> 16;
    return (unsigned short)u;
}
__device__ __forceinline__ float bflo(unsigned u) { return __builtin_bit_cast(float, u << 16); }
__device__ __forceinline__ float bfhi(unsigned u) { return __builtin_bit_cast(float, u & 0xffff0000u); }

__device__ __forceinline__ bf16x8 pack8(float4 a, float4 b) {
    bf16x8 r;
    r[0]=(short)f2bf(a.x); r[1]=(short)f2bf(a.y); r[2]=(short)f2bf(a.z); r[3]=(short)f2bf(a.w);
    r[4]=(short)f2bf(b.x); r[5]=(short)f2bf(b.y); r[6]=(short)f2bf(b.z); r[7]=(short)f2bf(b.w);
    return r;
}

// ---------------------------------------------------------------------------
// Edge logits via bf16 MFMA: C = Z Z^T + bias. 64x64 tile / 256-block.
// ---------------------------------------------------------------------------
__global__ __launch_bounds__(256) void edge_kernel(const unsigned short* __restrict__ zdb,
                                                   const float* __restrict__ bias,
                                                   float* __restrict__ out) {
    __shared__ float cstage[64][68];
    const int b  = blockIdx.z;
    const int tn = blockIdx.y * 64;
    const int tk = blockIdx.x * 64;
    const unsigned short* zb = zdb + (size_t)b * NMX * MD;
    const int tid = threadIdx.x, wave = tid >> 6, lane = tid & 63;
    const int l15 = lane & 15, k8 = (lane >> 4) * 8;

    const unsigned short* ap = zb + (size_t)(tn + wave * 16 + l15) * MD + k8;
    bf16x8 af0 = *(const bf16x8*)ap;
    bf16x8 af1 = *(const bf16x8*)(ap + 32);

    f32x4 acc[4];
    #pragma unroll
    for (int ct = 0; ct < 4; ct++) acc[ct] = (f32x4){0.f, 0.f, 0.f, 0.f};
    const unsigned short* bp = zb + (size_t)(tk + l15) * MD + k8;
    #pragma unroll
    for (int ct = 0; ct < 4; ct++) {
        bf16x8 b0 = *(const bf16x8*)(bp + (size_t)ct * 16 * MD);
        bf16x8 b1 = *(const bf16x8*)(bp + (size_t)ct * 16 * MD + 32);
        acc[ct] = __builtin_amdgcn_mfma_f32_16x16x32_bf16(af0, b0, acc[ct], 0, 0, 0);
        acc[ct] = __builtin_amdgcn_mfma_f32_16x16x32_bf16(af1, b1, acc[ct], 0, 0, 0);
    }
    #pragma unroll
    for (int ct = 0; ct < 4; ct++)
        #pragma unroll
        for (int i = 0; i < 4; i++)
            cstage[wave * 16 + (lane >> 4) * 4 + i][ct * 16 + l15] = acc[ct][i];
    __syncthreads();
    const float bi = bias[0];
    #pragma unroll
    for (int it = 0; it < 4; it++) {
        int f = tid + it * 256;
        int row = f >> 4, c4 = (f & 15) * 4;
        float4 v = *(const float4*)&cstage[row][c4];
        v.x += bi; v.y += bi; v.z += bi; v.w += bi;
        *(float4*)(out + ((size_t)b * NMX + tn + row) * NMX + tk + c4) = v;
    }
}

// ---------------------------------------------------------------------------
// Converters
// ---------------------------------------------------------------------------
__global__ __launch_bounds__(256) void cvt_kernel(const float* __restrict__ src,
                                                  unsigned short* __restrict__ dst,
                                                  int n4) {
    int i = blockIdx.x * 256 + threadIdx.x;
    if (i >= n4) return;
    float4 v = *(const float4*)(src + (size_t)i * 4);
    ushort4 o = {f2bf(v.x), f2bf(v.y), f2bf(v.z), f2bf(v.w)};
    *(ushort4*)(dst + (size_t)i * 4) = o;
}

__global__ __launch_bounds__(256) void tcvt_kernel(const float* __restrict__ src,
                                                   unsigned short* __restrict__ dst,
                                                   int K, int H) {
    int r = blockIdx.y;
    int i = blockIdx.x * 256 + threadIdx.x;
    if (i >= K * H) return;
    int k = i / H, h = i % H;
    float v = src[(size_t)r * K * H + i];
    dst[(size_t)r * K * H + (size_t)h * K + k] = f2bf(v);
}

// ---------------------------------------------------------------------------
// Fused MLP (two MFMA stages). BLK: input aggb in blocked [4][NN][32] layout.
// msgb output is ALWAYS blocked [4][NN][32]. MODE as before.
// ---------------------------------------------------------------------------
template <int K1, int MODE, bool BLK>
__global__ __launch_bounds__(256) void fused_kernel(
    const unsigned short* __restrict__ in,
    const unsigned short* __restrict__ Wt1,
    const float* __restrict__ b1,
    float* __restrict__ state,
    const unsigned short* __restrict__ Wt2,
    const float* __restrict__ b2,
    unsigned short* __restrict__ msgb,
    const float* __restrict__ Wout,
    const float* __restrict__ bout,
    float* __restrict__ node_out,
    int nrows)
{
    constexpr int KC1 = K1 / 32;
    __shared__ float cstage[64][132];
    __shared__ float sWout[MODE == 2 ? HD * FD : 1];
    const int tid = threadIdx.x, wave = tid >> 6, lane = tid & 63;
    const int l15 = lane & 15, k8 = (lane >> 4) * 8;
    const int rbase = blockIdx.x * 64;

    if constexpr (MODE == 2)
        for (int i = tid; i < HD * FD; i += 256) sWout[i] = Wout[i];

    // ---- stage 1 MFMA ----
    int rclamp = min(rbase + wave * 16 + l15, nrows - 1);
    bf16x8 af[KC1];
    #pragma unroll
    for (int c = 0; c < KC1; c++) {
        size_t off = BLK ? ((size_t)c * NN * 32 + (size_t)rclamp * 32 + k8)
                         : ((size_t)rclamp * K1 + (size_t)c * 32 + k8);
        af[c] = *(const bf16x8*)(in + off);
    }
    f32x4 acc[8];
    #pragma unroll
    for (int ct = 0; ct < 8; ct++) acc[ct] = (f32x4){0.f, 0.f, 0.f, 0.f};
    const unsigned short* bp = Wt1 + (size_t)l15 * K1 + k8;
    #pragma unroll
    for (int ct = 0; ct < 8; ct++)
        #pragma unroll
        for (int c = 0; c < KC1; c++) {
            bf16x8 bf = *(const bf16x8*)(bp + (size_t)ct * 16 * K1 + c * 32);
            acc[ct] = __builtin_amdgcn_mfma_f32_16x16x32_bf16(af[c], bf, acc[ct], 0, 0, 0);
        }
    #pragma unroll
    for (int ct = 0; ct < 8; ct++)
        #pragma unroll
        for (int i = 0; i < 4; i++)
            cstage[wave * 16 + (lane >> 4) * 4 + i][ct * 16 + l15] = acc[ct][i];
    __syncthreads();

    // ---- epilogue 1: bias+relu (+state_old) -> state_new ----
    #pragma unroll
    for (int it = 0; it < 8; it++) {
        int f = tid + it * 256;
        int row = f >> 5, c4 = (f & 31) * 4;
        int grow = rbase + row;
        if (grow < nrows) {
            float4 v = *(const float4*)&cstage[row][c4];
            float4 bb = *(const float4*)(b1 + c4);
            v.x = fmaxf(v.x + bb.x, 0.f);
            v.y = fmaxf(v.y + bb.y, 0.f);
            v.z = fmaxf(v.z + bb.z, 0.f);
            v.w = fmaxf(v.w + bb.w, 0.f);
            if constexpr (MODE >= 1) {
                float4 so = *(const float4*)(state + (size_t)grow * HD + c4);
                v.x += so.x; v.y += so.y; v.z += so.z; v.w += so.w;
            }
            if constexpr (MODE <= 1)
                *(float4*)(state + (size_t)grow * HD + c4) = v;
            *(float4*)&cstage[row][c4] = v;
        }
    }
    __syncthreads();

    if constexpr (MODE <= 1) {
        // ---- stage 2 MFMA: A-frags from updated cstage ----
        bf16x8 af2[4];
        #pragma unroll
        for (int c = 0; c < 4; c++) {
            float4 u0 = *(const float4*)&cstage[wave * 16 + l15][c * 32 + k8];
            float4 u1 = *(const float4*)&cstage[wave * 16 + l15][c * 32 + k8 + 4];
            af2[c] = pack8(u0, u1);
        }
        f32x4 acc2[8];
        #pragma unroll
        for (int ct = 0; ct < 8; ct++) acc2[ct] = (f32x4){0.f, 0.f, 0.f, 0.f};
        const unsigned short* bp2 = Wt2 + (size_t)l15 * HD + k8;
        #pragma unroll
        for (int ct = 0; ct < 8; ct++)
            #pragma unroll
            for (int c = 0; c < 4; c++) {
                bf16x8 bf = *(const bf16x8*)(bp2 + (size_t)ct * 16 * HD + c * 32);
                acc2[ct] = __builtin_amdgcn_mfma_f32_16x16x32_bf16(af2[c], bf, acc2[ct], 0, 0, 0);
            }
        __syncthreads();
        #pragma unroll
        for (int ct = 0; ct < 8; ct++)
            #pragma unroll
            for (int i = 0; i < 4; i++)
                cstage[wave * 16 + (lane >> 4) * 4 + i][ct * 16 + l15] = acc2[ct][i];
        __syncthreads();
        #pragma unroll
        for (int it = 0; it < 8; it++) {
            int f = tid + it * 256;
            int row = f >> 5, c4 = (f & 31) * 4;
            int grow = rbase + row;
            if (grow < nrows) {
                float4 v = *(const float4*)&cstage[row][c4];
                float4 bb = *(const float4*)(b2 + c4);
                v.x = fmaxf(v.x + bb.x, 0.f);
                v.y = fmaxf(v.y + bb.y, 0.f);
                v.z = fmaxf(v.z + bb.z, 0.f);
                v.w = fmaxf(v.w + bb.w, 0.f);
                ushort4 o = {f2bf(v.x), f2bf(v.y), f2bf(v.z), f2bf(v.w)};
                size_t off = (size_t)(c4 >> 5) * NN * 32 + (size_t)grow * 32 + (c4 & 31);
                *(ushort4*)(msgb + off) = o;
            }
        }
    } else {
        for (int i = tid; i < 64 * FD; i += 256) {
            int row = i / FD, ff = i - row * FD;
            int grow = rbase + row;
            if (grow < nrows) {
                float a = bout[ff];
                #pragma unroll 8
                for (int k = 0; k < HD; k++)
                    a += cstage[row][k] * sWout[k * FD + ff];
                node_out[(size_t)grow * FD + ff] = a;
            }
        }
    }
}

// ---------------------------------------------------------------------------
// CSR build via 2-phase MSD bucket sort — LDS atomics only.
// ---------------------------------------------------------------------------
__global__ __launch_bounds__(256) void p1c_kernel(const int* __restrict__ dst,
                                                  int* __restrict__ bh) {
    __shared__ int h[NH];
    const int b = blockIdx.x;
    for (int i = threadIdx.x; i < NH; i += 256) h[i] = 0;
    __syncthreads();
    const int e0 = b * BE;
    for (int i = threadIdx.x; i < BE; i += 256) {
        int e = e0 + i;
        if (e < EE) atomicAdd(&h[dst[e] >> 8], 1);
    }
    __syncthreads();
    for (int i = threadIdx.x; i < NH; i += 256) bh[i * NBL + b] = h[i];
}

__global__ __launch_bounds__(256) void scan1_kernel(const int* __restrict__ in,
                                                    int* __restrict__ incl,
                                                    int* __restrict__ bsum, int n) {
    __shared__ int s[256];
    int i = blockIdx.x * 256 + threadIdx.x;
    int t = threadIdx.x;
    s[t] = (i < n) ? in[i] : 0;
    __syncthreads();
    #pragma unroll
    for (int off = 1; off < 256; off <<= 1) {
        int x = (t >= off) ? s[t - off] : 0;
        __syncthreads();
        s[t] += x;
        __syncthreads();
    }
    if (i < n) incl[i] = s[t];
    if (t == 255) bsum[blockIdx.x] = s[255];
}

__global__ __launch_bounds__(256) void scan2_kernel(int* __restrict__ bsum, int nb) {
    __shared__ int s[256];
    int t = threadIdx.x;
    int orig = (t < nb) ? bsum[t] : 0;
    s[t] = orig;
    __syncthreads();
    #pragma unroll
    for (int off = 1; off < 256; off <<= 1) {
        int x = (t >= off) ? s[t - off] : 0;
        __syncthreads();
        s[t] += x;
        __syncthreads();
    }
    if (t < nb) bsum[t] = s[t] - orig;
}

__global__ __launch_bounds__(256) void scanex_kernel(const int* __restrict__ in,
                                                     const int* __restrict__ incl,
                                                     const int* __restrict__ bsum,
                                                     int* __restrict__ ex, int n) {
    int i = blockIdx.x * 256 + threadIdx.x;
    if (i < n) ex[i] = incl[i] - in[i] + bsum[blockIdx.x];
}

__global__ __launch_bounds__(256) void p1s_kernel(const int* __restrict__ src,
                                                  const int* __restrict__ dst,
                                                  const int* __restrict__ ex,
                                                  int2* __restrict__ sorted) {
    __shared__ int cur[NH];
    const int b = blockIdx.x;
    for (int i = threadIdx.x; i < NH; i += 256) cur[i] = ex[i * NBL + b];
    __syncthreads();
    const int e0 = b * BE;
    for (int i = threadIdx.x; i < BE; i += 256) {
        int e = e0 + i;
        if (e < EE) {
            int d = dst[e];
            int pos = atomicAdd(&cur[d >> 8], 1);
            sorted[pos] = make_int2(d, src[e]);
        }
    }
}

__global__ __launch_bounds__(256) void p2_kernel(const int2* __restrict__ sorted,
                                                 const int* __restrict__ ex,
                                                 int* __restrict__ row_ptr,
                                                 int* __restrict__ colsrc) {
    __shared__ int hist[256];
    __shared__ int scanb[256];
    __shared__ int cur[256];
    const int h = blockIdx.x;
    const int t = threadIdx.x;
    const int base = ex[h * NBL];
    const int endp = (h == NH - 1) ? EE : ex[(h + 1) * NBL];
    const int cnt  = endp - base;
    hist[t] = 0;
    __syncthreads();
    for (int i = t; i < cnt; i += 256)
        atomicAdd(&hist[sorted[base + i].x & 255], 1);
    __syncthreads();
    scanb[t] = hist[t];
    __syncthreads();
    #pragma unroll
    for (int off = 1; off < 256; off <<= 1) {
        int x = (t >= off) ? scanb[t - off] : 0;
        __syncthreads();
        scanb[t] += x;
        __syncthreads();
    }
    int excl = scanb[t] - hist[t];
    cur[t] = excl;
    int v = h * 256 + t;
    if (v < NN) row_ptr[v] = base + excl;
    if (h == NH - 1 && t == 0) row_ptr[NN] = EE;
    __syncthreads();
    for (int i = t; i < cnt; i += 256) {
        int2 pr = sorted[base + i];
        int pos = base + atomicAdd(&cur[pr.x & 255], 1);
        colsrc[pos] = pr.y;
    }
}

// ---------------------------------------------------------------------------
// Gather v5: pass-split (L2-resident 3.2MB slice) x wave-per-node engine.
// Blocked layout [pass][node][4 u32x4]. Lane: e = lane>>2 (16 edges),
// q = lane&3 (16B quad). One dwordx4 covers 16 complete 64B slices.
// Non-temporal colsrc loads / agg stores (ext_vector type for the builtin).
// ---------------------------------------------------------------------------
__global__ __launch_bounds__(256) void gather_kernel(const int* __restrict__ rp,
                                                     const int* __restrict__ colsrc,
                                                     const u32x4* __restrict__ msg4,
                                                     u32x4* __restrict__ agg4) {
    const int pass = blockIdx.x / GNBP;
    const int nb   = blockIdx.x - pass * GNBP;
    const int v    = nb * 4 + (threadIdx.x >> 6);
    if (v >= NN) return;
    const int lane = threadIdx.x & 63;
    const int e = lane >> 2, q = lane & 3;
    const int beg = rp[v], end = rp[v + 1];
    const u32x4* mbase = msg4 + (size_t)pass * NN * 4 + q;

    float a[8];
    #pragma unroll
    for (int i = 0; i < 8; i++) a[i] = 0.f;

    int j = beg;
    for (; j + 31 < end; j += 32) {
        int c0 = __builtin_nontemporal_load(&colsrc[j + e]);
        int c1 = __builtin_nontemporal_load(&colsrc[j + 16 + e]);
        u32x4 u = mbase[(size_t)c0 * 4];
        u32x4 w = mbase[(size_t)c1 * 4];
        a[0] += bflo(u.x); a[1] += bfhi(u.x);
        a[2] += bflo(u.y); a[3] += bfhi(u.y);
        a[4] += bflo(u.z); a[5] += bfhi(u.z);
        a[6] += bflo(u.w); a[7] += bfhi(u.w);
        a[0] += bflo(w.x); a[1] += bfhi(w.x);
        a[2] += bflo(w.y); a[3] += bfhi(w.y);
        a[4] += bflo(w.z); a[5] += bfhi(w.z);
        a[6] += bflo(w.w); a[7] += bfhi(w.w);
    }
    for (; j < end; j += 16) {
        if (j + e < end) {
            int c0 = __builtin_nontemporal_load(&colsrc[j + e]);
            u32x4 u = mbase[(size_t)c0 * 4];
            a[0] += bflo(u.x); a[1] += bfhi(u.x);
            a[2] += bflo(u.y); a[3] += bfhi(u.y);
            a[4] += bflo(u.z); a[5] += bfhi(u.z);
            a[6] += bflo(u.w); a[7] += bfhi(u.w);
        }
    }
    // reduce across the 16 e-groups (lane bits 2..5)
    #pragma unroll
    for (int i = 0; i < 8; i++) {
        a[i] += __shfl_xor(a[i], 4);
        a[i] += __shfl_xor(a[i], 8);
        a[i] += __shfl_xor(a[i], 16);
        a[i] += __shfl_xor(a[i], 32);
    }
    if (lane < 4) {
        u32x4 o;
        o.x = (unsigned)f2bf(a[0]) | ((unsigned)f2bf(a[1]) << 16);
        o.y = (unsigned)f2bf(a[2]) | ((unsigned)f2bf(a[3]) << 16);
        o.z = (unsigned)f2bf(a[4]) | ((unsigned)f2bf(a[5]) << 16);
        o.w = (unsigned)f2bf(a[6]) | ((unsigned)f2bf(a[7]) << 16);
        __builtin_nontemporal_store(o, &agg4[(size_t)pass * NN * 4 + (size_t)v * 4 + lane]);
    }
}

extern "C" void kernel_launch(void* const* d_in, const int* in_sizes, int n_in,
                              void* d_out, int out_size, void* d_ws, size_t ws_size,
                              hipStream_t stream) {
    const float* z          = (const float*)d_in[0];
    const int*   edge_index = (const int*)  d_in[1];
    const float* z_dense    = (const float*)d_in[2];
    const float* bias       = (const float*)d_in[3];
    const float* W_in       = (const float*)d_in[4];
    const float* b_in       = (const float*)d_in[5];
    const float* W_msg      = (const float*)d_in[6];
    const float* b_msg      = (const float*)d_in[7];
    const float* W_upd      = (const float*)d_in[8];
    const float* b_upd      = (const float*)d_in[9];
    const float* W_out      = (const float*)d_in[10];
    const float* b_out      = (const float*)d_in[11];

    float* out      = (float*)d_out;
    float* edge_out = out;
    float* node_out = out + (size_t)BG * NMX * NMX;

    // ---- workspace ----
    char* p = (char*)d_ws;
    float* state = (float*)p;                     p += (size_t)NN * HD * 4;
    unsigned short* msgb   = (unsigned short*)p;  p += (size_t)NN * HD * 2;  // blocked [4][NN][32]
    unsigned short* aggb   = (unsigned short*)p;  p += (size_t)NN * HD * 2;  // blocked [4][NN][32]
    unsigned short* zb     = (unsigned short*)p;  p += (size_t)NN * MD * 2;
    unsigned short* zdb    = (unsigned short*)p;  p += (size_t)BG * NMX * MD * 2;
    unsigned short* wt_in  = (unsigned short*)p;  p += (size_t)HD * MD * 2;
    unsigned short* wt_msg = (unsigned short*)p;  p += (size_t)RR * HD * HD * 2;
    unsigned short* wt_upd = (unsigned short*)p;  p += (size_t)RR * HD * HD * 2;
    int*  bh      = (int*)p;                      p += (size_t)NS * 4;
    int*  incl    = (int*)p;                      p += (size_t)NS * 4;
    int*  exsc    = (int*)p;                      p += (size_t)NS * 4;
    int*  row_ptr = (int*)p;                      p += (size_t)(NN + 1) * 4;
    int*  colsrc  = (int*)p;                      p += (size_t)EE * 4;
    int2* sorted  = (int2*)p;                     p += (size_t)EE * 8;
    int*  bsum    = (int*)p;

    const int* src = edge_index;
    const int* dst = edge_index + EE;

    // ---- edge path ----
    cvt_kernel<<<(BG * NMX * MD / 4 + 255) / 256, 256, 0, stream>>>(
        z_dense, zdb, BG * NMX * MD / 4);
    dim3 eg(NMX / 64, NMX / 64, BG);
    edge_kernel<<<eg, 256, 0, stream>>>(zdb, bias, edge_out);

    // ---- conversions ----
    cvt_kernel<<<(NN * MD / 4 + 255) / 256, 256, 0, stream>>>(z, zb, NN * MD / 4);
    tcvt_kernel<<<dim3((MD * HD + 255) / 256, 1), 256, 0, stream>>>(W_in, wt_in, MD, HD);
    tcvt_kernel<<<dim3((HD * HD + 255) / 256, RR), 256, 0, stream>>>(W_msg, wt_msg, HD, HD);
    tcvt_kernel<<<dim3((HD * HD + 255) / 256, RR), 256, 0, stream>>>(W_upd, wt_upd, HD, HD);

    // ---- CSR build: MSD bucket sort (LDS atomics only) ----
    p1c_kernel<<<NBL, 256, 0, stream>>>(dst, bh);
    scan1_kernel<<<NSB, 256, 0, stream>>>(bh, incl, bsum, NS);
    scan2_kernel<<<1, 256, 0, stream>>>(bsum, NSB);
    scanex_kernel<<<NSB, 256, 0, stream>>>(bh, incl, bsum, exsc, NS);
    p1s_kernel<<<NBL, 256, 0, stream>>>(src, dst, exsc, sorted);
    p2_kernel<<<NH, 256, 0, stream>>>(sorted, exsc, row_ptr, colsrc);

    // ---- node pipeline ----
    const int MG = (NN + 63) / 64;
    const int GG = NPASS * GNBP;

    fused_kernel<MD, 0, false><<<MG, 256, 0, stream>>>(
        zb, wt_in, b_in, state,
        wt_msg, b_msg, msgb, nullptr, nullptr, nullptr, NN);

    for (int r = 0; r < RR - 1; r++) {
        gather_kernel<<<GG, 256, 0, stream>>>(row_ptr, colsrc,
                                              (const u32x4*)msgb, (u32x4*)aggb);
        fused_kernel<HD, 1, true><<<MG, 256, 0, stream>>>(
            aggb, wt_upd + (size_t)r * HD * HD, b_upd + (size_t)r * HD, state,
            wt_msg + (size_t)(r + 1) * HD * HD, b_msg + (size_t)(r + 1) * HD,
            msgb, nullptr, nullptr, nullptr, NN);
    }
    gather_kernel<<<GG, 256, 0, stream>>>(row_ptr, colsrc,
                                          (const u32x4*)msgb, (u32x4*)aggb);
    fused_kernel<HD, 2, true><<<MG, 256, 0, stream>>>(
        aggb, wt_upd + (size_t)(RR - 1) * HD * HD, b_upd + (size_t)(RR - 1) * HD, state,
        nullptr, nullptr, nullptr, W_out, b_out, node_out, NN);
}

// Round 12
// 526.065 us; speedup vs baseline: 1.0235x; 1.0235x over previous
//
#include <hip/hip_runtime.h>
#include <cstdint>

#define NN  50000
#define MD  64
#define HD  128
#define RR  4
#define FD  7
#define EE  800000
#define BG  32
#define NMX 512

// MSD bucket sort geometry
#define NH   196
#define NBL  196
#define BE   4096
#define NS   (NH * NBL)
#define NSB  ((NS + 255) / 256)

typedef __attribute__((ext_vector_type(8))) short bf16x8;
typedef __attribute__((ext_vector_type(4))) float f32x4;
typedef __attribute__((ext_vector_type(4))) unsigned u32x4;

__device__ __forceinline__ unsigned short f2bf(float f) {
    unsigned u = __builtin_bit_cast(unsigned, f);
    u = (u + 0x7fffu + ((u >> 16) & 1u)) >> 16;
    return (unsigned short)u;
}
__device__ __forceinline__ float bflo(unsigned u) { return __builtin_bit_cast(float, u << 16); }
__device__ __forceinline__ float bfhi(unsigned u) { return __builtin_bit_cast(float, u & 0xffff0000u); }

__device__ __forceinline__ bf16x8 pack8(float4 a, float4 b) {
    bf16x8 r;
    r[0]=(short)f2bf(a.x); r[1]=(short)f2bf(a.y); r[2]=(short)f2bf(a.z); r[3]=(short)f2bf(a.w);
    r[4]=(short)f2bf(b.x); r[5]=(short)f2bf(b.y); r[6]=(short)f2bf(b.z); r[7]=(short)f2bf(b.w);
    return r;
}

// ---------------------------------------------------------------------------
// Edge logits via bf16 MFMA: C = Z Z^T + bias. 64x64 tile / 256-block.
// ---------------------------------------------------------------------------
__global__ __launch_bounds__(256) void edge_kernel(const unsigned short* __restrict__ zdb,
                                                   const float* __restrict__ bias,
                                                   float* __restrict__ out) {
    __shared__ float cstage[64][68];
    const int b  = blockIdx.z;
    const int tn = blockIdx.y * 64;
    const int tk = blockIdx.x * 64;
    const unsigned short* zb = zdb + (size_t)b * NMX * MD;
    const int tid = threadIdx.x, wave = tid >> 6, lane = tid & 63;
    const int l15 = lane & 15, k8 = (lane >> 4) * 8;

    const unsigned short* ap = zb + (size_t)(tn + wave * 16 + l15) * MD + k8;
    bf16x8 af0 = *(const bf16x8*)ap;
    bf16x8 af1 = *(const bf16x8*)(ap + 32);

    f32x4 acc[4];
    #pragma unroll
    for (int ct = 0; ct < 4; ct++) acc[ct] = (f32x4){0.f, 0.f, 0.f, 0.f};
    const unsigned short* bp = zb + (size_t)(tk + l15) * MD + k8;
    #pragma unroll
    for (int ct = 0; ct < 4; ct++) {
        bf16x8 b0 = *(const bf16x8*)(bp + (size_t)ct * 16 * MD);
        bf16x8 b1 = *(const bf16x8*)(bp + (size_t)ct * 16 * MD + 32);
        acc[ct] = __builtin_amdgcn_mfma_f32_16x16x32_bf16(af0, b0, acc[ct], 0, 0, 0);
        acc[ct] = __builtin_amdgcn_mfma_f32_16x16x32_bf16(af1, b1, acc[ct], 0, 0, 0);
    }
    #pragma unroll
    for (int ct = 0; ct < 4; ct++)
        #pragma unroll
        for (int i = 0; i < 4; i++)
            cstage[wave * 16 + (lane >> 4) * 4 + i][ct * 16 + l15] = acc[ct][i];
    __syncthreads();
    const float bi = bias[0];
    #pragma unroll
    for (int it = 0; it < 4; it++) {
        int f = tid + it * 256;
        int row = f >> 4, c4 = (f & 15) * 4;
        float4 v = *(const float4*)&cstage[row][c4];
        v.x += bi; v.y += bi; v.z += bi; v.w += bi;
        *(float4*)(out + ((size_t)b * NMX + tn + row) * NMX + tk + c4) = v;
    }
}

// ---------------------------------------------------------------------------
// Merged converters
// ---------------------------------------------------------------------------
__global__ __launch_bounds__(256) void cvt2_kernel(const float* __restrict__ a,
                                                   unsigned short* __restrict__ da, int n4a,
                                                   const float* __restrict__ b,
                                                   unsigned short* __restrict__ db, int n4b) {
    int i = blockIdx.x * 256 + threadIdx.x;
    if (i < n4a) {
        float4 v = *(const float4*)(a + (size_t)i * 4);
        ushort4 o = {f2bf(v.x), f2bf(v.y), f2bf(v.z), f2bf(v.w)};
        *(ushort4*)(da + (size_t)i * 4) = o;
    } else if (i < n4a + n4b) {
        int k = i - n4a;
        float4 v = *(const float4*)(b + (size_t)k * 4);
        ushort4 o = {f2bf(v.x), f2bf(v.y), f2bf(v.z), f2bf(v.w)};
        *(ushort4*)(db + (size_t)k * 4) = o;
    }
}

__global__ __launch_bounds__(256) void tcvt_all_kernel(const float* __restrict__ W_in,
                                                       const float* __restrict__ W_msg,
                                                       const float* __restrict__ W_upd,
                                                       unsigned short* __restrict__ wt_in,
                                                       unsigned short* __restrict__ wt_msg,
                                                       unsigned short* __restrict__ wt_upd) {
    const int y = blockIdx.y;
    const float* src; unsigned short* dst; int K;
    if (y == 0)        { src = W_in;                      dst = wt_in;                       K = MD; }
    else if (y <= RR)  { int r = y - 1;     src = W_msg + (size_t)r * HD * HD; dst = wt_msg + (size_t)r * HD * HD; K = HD; }
    else               { int r = y - 1 - RR; src = W_upd + (size_t)r * HD * HD; dst = wt_upd + (size_t)r * HD * HD; K = HD; }
    int i = blockIdx.x * 256 + threadIdx.x;
    if (i >= K * HD) return;
    int k = i / HD, h = i % HD;
    dst[(size_t)h * K + k] = f2bf(src[i]);
}

// ---------------------------------------------------------------------------
// Fused MLP (two MFMA stages), flat [n][K] layouts.
// GATH: stage-1 input rows gathered in-kernel from msg4 (round-r buffer) via
// CSR into LDS atile (v4 engine per wave). msgb (round r+1) is a SEPARATE
// buffer (double-buffered by caller) -> no read/write race.
// ---------------------------------------------------------------------------
template <int K1, int MODE, bool GATH>
__global__ __launch_bounds__(256) void fused_kernel(
    const unsigned short* __restrict__ in,
    const int* __restrict__ rp,
    const int* __restrict__ colsrc,
    const u32x4* __restrict__ msg4,
    const unsigned short* __restrict__ Wt1,
    const float* __restrict__ b1,
    float* __restrict__ state,
    const unsigned short* __restrict__ Wt2,
    const float* __restrict__ b2,
    unsigned short* __restrict__ msgb,
    const float* __restrict__ Wout,
    const float* __restrict__ bout,
    float* __restrict__ node_out,
    int nrows)
{
    constexpr int KC1 = K1 / 32;
    __shared__ float cstage[64][132];
    __shared__ unsigned short atile[GATH ? 64 : 1][GATH ? 136 : 8];
    __shared__ float sWout[MODE == 2 ? HD * FD : 1];
    const int tid = threadIdx.x, wave = tid >> 6, lane = tid & 63;
    const int l15 = lane & 15, k8 = (lane >> 4) * 8;
    const int rbase = blockIdx.x * 64;

    if constexpr (MODE == 2)
        for (int i = tid; i < HD * FD; i += 256) sWout[i] = Wout[i];

    // ---- gather phase (GATH): wave w gathers rows w*16..w*16+15 into atile ----
    if constexpr (GATH) {
        const int e = lane >> 4, q = lane & 15;
        for (int t = 0; t < 16; t++) {
            const int v = rbase + wave * 16 + t;
            float a[8];
            #pragma unroll
            for (int i = 0; i < 8; i++) a[i] = 0.f;
            if (v < nrows) {
                const int beg = rp[v], end = rp[v + 1];
                int j = beg;
                for (; j + 7 < end; j += 8) {
                    int c0 = colsrc[j + e];
                    int c1 = colsrc[j + 4 + e];
                    u32x4 u = msg4[(size_t)c0 * 16 + q];
                    u32x4 w = msg4[(size_t)c1 * 16 + q];
                    a[0] += bflo(u.x); a[1] += bfhi(u.x);
                    a[2] += bflo(u.y); a[3] += bfhi(u.y);
                    a[4] += bflo(u.z); a[5] += bfhi(u.z);
                    a[6] += bflo(u.w); a[7] += bfhi(u.w);
                    a[0] += bflo(w.x); a[1] += bfhi(w.x);
                    a[2] += bflo(w.y); a[3] += bfhi(w.y);
                    a[4] += bflo(w.z); a[5] += bfhi(w.z);
                    a[6] += bflo(w.w); a[7] += bfhi(w.w);
                }
                for (; j < end; j += 4) {
                    if (j + e < end) {
                        u32x4 u = msg4[(size_t)colsrc[j + e] * 16 + q];
                        a[0] += bflo(u.x); a[1] += bfhi(u.x);
                        a[2] += bflo(u.y); a[3] += bfhi(u.y);
                        a[4] += bflo(u.z); a[5] += bfhi(u.z);
                        a[6] += bflo(u.w); a[7] += bfhi(u.w);
                    }
                }
                #pragma unroll
                for (int i = 0; i < 8; i++) {
                    a[i] += __shfl_xor(a[i], 16);
                    a[i] += __shfl_xor(a[i], 32);
                }
            }
            if (lane < 16) {
                bf16x8 o;
                #pragma unroll
                for (int i = 0; i < 8; i++) o[i] = (short)f2bf(a[i]);
                *(bf16x8*)&atile[wave * 16 + t][lane * 8] = o;
            }
        }
        // no barrier: stage 1 below reads only rows this wave wrote
    }

    // ---- stage 1 MFMA ----
    bf16x8 af[KC1];
    if constexpr (GATH) {
        #pragma unroll
        for (int c = 0; c < KC1; c++)
            af[c] = *(const bf16x8*)&atile[wave * 16 + l15][c * 32 + k8];
    } else {
        int rclamp = min(rbase + wave * 16 + l15, nrows - 1);
        #pragma unroll
        for (int c = 0; c < KC1; c++)
            af[c] = *(const bf16x8*)(in + (size_t)rclamp * K1 + (size_t)c * 32 + k8);
    }
    f32x4 acc[8];
    #pragma unroll
    for (int ct = 0; ct < 8; ct++) acc[ct] = (f32x4){0.f, 0.f, 0.f, 0.f};
    const unsigned short* bp = Wt1 + (size_t)l15 * K1 + k8;
    #pragma unroll
    for (int ct = 0; ct < 8; ct++)
        #pragma unroll
        for (int c = 0; c < KC1; c++) {
            bf16x8 bf = *(const bf16x8*)(bp + (size_t)ct * 16 * K1 + c * 32);
            acc[ct] = __builtin_amdgcn_mfma_f32_16x16x32_bf16(af[c], bf, acc[ct], 0, 0, 0);
        }
    #pragma unroll
    for (int ct = 0; ct < 8; ct++)
        #pragma unroll
        for (int i = 0; i < 4; i++)
            cstage[wave * 16 + (lane >> 4) * 4 + i][ct * 16 + l15] = acc[ct][i];
    __syncthreads();

    // ---- epilogue 1: bias+relu (+state_old) -> state_new ----
    #pragma unroll
    for (int it = 0; it < 8; it++) {
        int f = tid + it * 256;
        int row = f >> 5, c4 = (f & 31) * 4;
        int grow = rbase + row;
        if (grow < nrows) {
            float4 v = *(const float4*)&cstage[row][c4];
            float4 bb = *(const float4*)(b1 + c4);
            v.x = fmaxf(v.x + bb.x, 0.f);
            v.y = fmaxf(v.y + bb.y, 0.f);
            v.z = fmaxf(v.z + bb.z, 0.f);
            v.w = fmaxf(v.w + bb.w, 0.f);
            if constexpr (MODE >= 1) {
                float4 so = *(const float4*)(state + (size_t)grow * HD + c4);
                v.x += so.x; v.y += so.y; v.z += so.z; v.w += so.w;
            }
            if constexpr (MODE <= 1)
                *(float4*)(state + (size_t)grow * HD + c4) = v;
            *(float4*)&cstage[row][c4] = v;
        }
    }
    __syncthreads();

    if constexpr (MODE <= 1) {
        // ---- stage 2 MFMA: A-frags from updated cstage ----
        bf16x8 af2[4];
        #pragma unroll
        for (int c = 0; c < 4; c++) {
            float4 u0 = *(const float4*)&cstage[wave * 16 + l15][c * 32 + k8];
            float4 u1 = *(const float4*)&cstage[wave * 16 + l15][c * 32 + k8 + 4];
            af2[c] = pack8(u0, u1);
        }
        f32x4 acc2[8];
        #pragma unroll
        for (int ct = 0; ct < 8; ct++) acc2[ct] = (f32x4){0.f, 0.f, 0.f, 0.f};
        const unsigned short* bp2 = Wt2 + (size_t)l15 * HD + k8;
        #pragma unroll
        for (int ct = 0; ct < 8; ct++)
            #pragma unroll
            for (int c = 0; c < 4; c++) {
                bf16x8 bf = *(const bf16x8*)(bp2 + (size_t)ct * 16 * HD + c * 32);
                acc2[ct] = __builtin_amdgcn_mfma_f32_16x16x32_bf16(af2[c], bf, acc2[ct], 0, 0, 0);
            }
        __syncthreads();
        #pragma unroll
        for (int ct = 0; ct < 8; ct++)
            #pragma unroll
            for (int i = 0; i < 4; i++)
                cstage[wave * 16 + (lane >> 4) * 4 + i][ct * 16 + l15] = acc2[ct][i];
        __syncthreads();
        #pragma unroll
        for (int it = 0; it < 8; it++) {
            int f = tid + it * 256;
            int row = f >> 5, c4 = (f & 31) * 4;
            int grow = rbase + row;
            if (grow < nrows) {
                float4 v = *(const float4*)&cstage[row][c4];
                float4 bb = *(const float4*)(b2 + c4);
                v.x = fmaxf(v.x + bb.x, 0.f);
                v.y = fmaxf(v.y + bb.y, 0.f);
                v.z = fmaxf(v.z + bb.z, 0.f);
                v.w = fmaxf(v.w + bb.w, 0.f);
                ushort4 o = {f2bf(v.x), f2bf(v.y), f2bf(v.z), f2bf(v.w)};
                *(ushort4*)(msgb + (size_t)grow * HD + c4) = o;
            }
        }
    } else {
        for (int i = tid; i < 64 * FD; i += 256) {
            int row = i / FD, ff = i - row * FD;
            int grow = rbase + row;
            if (grow < nrows) {
                float a = bout[ff];
                #pragma unroll 8
                for (int k = 0; k < HD; k++)
                    a += cstage[row][k] * sWout[k * FD + ff];
                node_out[(size_t)grow * FD + ff] = a;
            }
        }
    }
}

// ---------------------------------------------------------------------------
// CSR build via 2-phase MSD bucket sort — LDS atomics only.
// ---------------------------------------------------------------------------
__global__ __launch_bounds__(256) void p1c_kernel(const int* __restrict__ dst,
                                                  int* __restrict__ bh) {
    __shared__ int h[NH];
    const int b = blockIdx.x;
    for (int i = threadIdx.x; i < NH; i += 256) h[i] = 0;
    __syncthreads();
    const int e0 = b * BE;
    for (int i = threadIdx.x; i < BE; i += 256) {
        int e = e0 + i;
        if (e < EE) atomicAdd(&h[dst[e] >> 8], 1);
    }
    __syncthreads();
    for (int i = threadIdx.x; i < NH; i += 256) bh[i * NBL + b] = h[i];
}

__global__ __launch_bounds__(256) void scan1_kernel(const int* __restrict__ in,
                                                    int* __restrict__ incl,
                                                    int* __restrict__ bsum, int n) {
    __shared__ int s[256];
    int i = blockIdx.x * 256 + threadIdx.x;
    int t = threadIdx.x;
    s[t] = (i < n) ? in[i] : 0;
    __syncthreads();
    #pragma unroll
    for (int off = 1; off < 256; off <<= 1) {
        int x = (t >= off) ? s[t - off] : 0;
        __syncthreads();
        s[t] += x;
        __syncthreads();
    }
    if (i < n) incl[i] = s[t];
    if (t == 255) bsum[blockIdx.x] = s[255];
}

__global__ __launch_bounds__(256) void scan2_kernel(int* __restrict__ bsum, int nb) {
    __shared__ int s[256];
    int t = threadIdx.x;
    int orig = (t < nb) ? bsum[t] : 0;
    s[t] = orig;
    __syncthreads();
    #pragma unroll
    for (int off = 1; off < 256; off <<= 1) {
        int x = (t >= off) ? s[t - off] : 0;
        __syncthreads();
        s[t] += x;
        __syncthreads();
    }
    if (t < nb) bsum[t] = s[t] - orig;
}

__global__ __launch_bounds__(256) void scanex_kernel(const int* __restrict__ in,
                                                     const int* __restrict__ incl,
                                                     const int* __restrict__ bsum,
                                                     int* __restrict__ ex, int n) {
    int i = blockIdx.x * 256 + threadIdx.x;
    if (i < n) ex[i] = incl[i] - in[i] + bsum[blockIdx.x];
}

__global__ __launch_bounds__(256) void p1s_kernel(const int* __restrict__ src,
                                                  const int* __restrict__ dst,
                                                  const int* __restrict__ ex,
                                                  int2* __restrict__ sorted) {
    __shared__ int cur[NH];
    const int b = blockIdx.x;
    for (int i = threadIdx.x; i < NH; i += 256) cur[i] = ex[i * NBL + b];
    __syncthreads();
    const int e0 = b * BE;
    for (int i = threadIdx.x; i < BE; i += 256) {
        int e = e0 + i;
        if (e < EE) {
            int d = dst[e];
            int pos = atomicAdd(&cur[d >> 8], 1);
            sorted[pos] = make_int2(d, src[e]);
        }
    }
}

__global__ __launch_bounds__(256) void p2_kernel(const int2* __restrict__ sorted,
                                                 const int* __restrict__ ex,
                                                 int* __restrict__ row_ptr,
                                                 int* __restrict__ colsrc) {
    __shared__ int hist[256];
    __shared__ int scanb[256];
    __shared__ int cur[256];
    const int h = blockIdx.x;
    const int t = threadIdx.x;
    const int base = ex[h * NBL];
    const int endp = (h == NH - 1) ? EE : ex[(h + 1) * NBL];
    const int cnt  = endp - base;
    hist[t] = 0;
    __syncthreads();
    for (int i = t; i < cnt; i += 256)
        atomicAdd(&hist[sorted[base + i].x & 255], 1);
    __syncthreads();
    scanb[t] = hist[t];
    __syncthreads();
    #pragma unroll
    for (int off = 1; off < 256; off <<= 1) {
        int x = (t >= off) ? scanb[t - off] : 0;
        __syncthreads();
        scanb[t] += x;
        __syncthreads();
    }
    int excl = scanb[t] - hist[t];
    cur[t] = excl;
    int v = h * 256 + t;
    if (v < NN) row_ptr[v] = base + excl;
    if (h == NH - 1 && t == 0) row_ptr[NN] = EE;
    __syncthreads();
    for (int i = t; i < cnt; i += 256) {
        int2 pr = sorted[base + i];
        int pos = base + atomicAdd(&cur[pr.x & 255], 1);
        colsrc[pos] = pr.y;
    }
}

extern "C" void kernel_launch(void* const* d_in, const int* in_sizes, int n_in,
                              void* d_out, int out_size, void* d_ws, size_t ws_size,
                              hipStream_t stream) {
    const float* z          = (const float*)d_in[0];
    const int*   edge_index = (const int*)  d_in[1];
    const float* z_dense    = (const float*)d_in[2];
    const float* bias       = (const float*)d_in[3];
    const float* W_in       = (const float*)d_in[4];
    const float* b_in       = (const float*)d_in[5];
    const float* W_msg      = (const float*)d_in[6];
    const float* b_msg      = (const float*)d_in[7];
    const float* W_upd      = (const float*)d_in[8];
    const float* b_upd      = (const float*)d_in[9];
    const float* W_out      = (const float*)d_in[10];
    const float* b_out      = (const float*)d_in[11];

    float* out      = (float*)d_out;
    float* edge_out = out;
    float* node_out = out + (size_t)BG * NMX * NMX;

    // ---- workspace (flat layouts; msg double-buffered) ----
    char* p = (char*)d_ws;
    float* state = (float*)p;                     p += (size_t)NN * HD * 4;
    unsigned short* msgA   = (unsigned short*)p;  p += (size_t)NN * HD * 2;
    unsigned short* msgB   = (unsigned short*)p;  p += (size_t)NN * HD * 2;
    unsigned short* zb     = (unsigned short*)p;  p += (size_t)NN * MD * 2;
    unsigned short* zdb    = (unsigned short*)p;  p += (size_t)BG * NMX * MD * 2;
    unsigned short* wt_in  = (unsigned short*)p;  p += (size_t)HD * MD * 2;
    unsigned short* wt_msg = (unsigned short*)p;  p += (size_t)RR * HD * HD * 2;
    unsigned short* wt_upd = (unsigned short*)p;  p += (size_t)RR * HD * HD * 2;
    int*  bh      = (int*)p;                      p += (size_t)NS * 4;
    int*  incl    = (int*)p;                      p += (size_t)NS * 4;
    int*  exsc    = (int*)p;                      p += (size_t)NS * 4;
    int*  row_ptr = (int*)p;                      p += (size_t)(NN + 1) * 4;
    int*  colsrc  = (int*)p;                      p += (size_t)EE * 4;
    int2* sorted  = (int2*)p;                     p += (size_t)EE * 8;
    int*  bsum    = (int*)p;

    const int* src = edge_index;
    const int* dst = edge_index + EE;

    // ---- conversions (merged) ----
    const int n4zd = BG * NMX * MD / 4;
    const int n4z  = NN * MD / 4;
    cvt2_kernel<<<(n4zd + n4z + 255) / 256, 256, 0, stream>>>(
        z_dense, zdb, n4zd, z, zb, n4z);

    // ---- edge path ----
    dim3 eg(NMX / 64, NMX / 64, BG);
    edge_kernel<<<eg, 256, 0, stream>>>(zdb, bias, edge_out);

    tcvt_all_kernel<<<dim3((HD * HD + 255) / 256, 1 + 2 * RR), 256, 0, stream>>>(
        W_in, W_msg, W_upd, wt_in, wt_msg, wt_upd);

    // ---- CSR build: MSD bucket sort (LDS atomics only) ----
    p1c_kernel<<<NBL, 256, 0, stream>>>(dst, bh);
    scan1_kernel<<<NSB, 256, 0, stream>>>(bh, incl, bsum, NS);
    scan2_kernel<<<1, 256, 0, stream>>>(bsum, NSB);
    scanex_kernel<<<NSB, 256, 0, stream>>>(bh, incl, bsum, exsc, NS);
    p1s_kernel<<<NBL, 256, 0, stream>>>(src, dst, exsc, sorted);
    p2_kernel<<<NH, 256, 0, stream>>>(sorted, exsc, row_ptr, colsrc);

    // ---- node pipeline (msg ping-pong: A -> B -> A -> B -> final reads B) ----
    const int MG = (NN + 63) / 64;

    fused_kernel<MD, 0, false><<<MG, 256, 0, stream>>>(
        zb, nullptr, nullptr, nullptr, wt_in, b_in, state,
        wt_msg, b_msg, msgA, nullptr, nullptr, nullptr, NN);

    unsigned short* ping = msgA;   // round-r messages (read)
    unsigned short* pong = msgB;   // round-(r+1) messages (write)
    for (int r = 0; r < RR - 1; r++) {
        fused_kernel<HD, 1, true><<<MG, 256, 0, stream>>>(
            nullptr, row_ptr, colsrc, (const u32x4*)ping,
            wt_upd + (size_t)r * HD * HD, b_upd + (size_t)r * HD, state,
            wt_msg + (size_t)(r + 1) * HD * HD, b_msg + (size_t)(r + 1) * HD,
            pong, nullptr, nullptr, nullptr, NN);
        unsigned short* tmp = ping; ping = pong; pong = tmp;
    }
    fused_kernel<HD, 2, true><<<MG, 256, 0, stream>>>(
        nullptr, row_ptr, colsrc, (const u32x4*)ping,
        wt_upd + (size_t)(RR - 1) * HD * HD, b_upd + (size_t)(RR - 1) * HD, state,
        nullptr, nullptr, nullptr, W_out, b_out, node_out, NN);
}

// Round 13
// 351.081 us; speedup vs baseline: 1.5337x; 1.4984x over previous
//
#include <hip/hip_runtime.h>
#include <cstdint>

#define NN  50000
#define MD  64
#define HD  128
#define RR  4
#define FD  7
#define EE  800000
#define BG  32
#define NMX 512

// MSD bucket sort geometry
#define NH   196
#define NBL  196
#define BE   4096
#define NS   (NH * NBL)
#define NSB  ((NS + 255) / 256)

typedef __attribute__((ext_vector_type(8))) short bf16x8;
typedef __attribute__((ext_vector_type(4))) float f32x4;
typedef __attribute__((ext_vector_type(4))) unsigned u32x4;

__device__ __forceinline__ unsigned short f2bf(float f) {
    unsigned u = __builtin_bit_cast(unsigned, f);
    u = (u + 0x7fffu + ((u >> 16) & 1u)) >> 16;
    return (unsigned short)u;
}
__device__ __forceinline__ float bflo(unsigned u) { return __builtin_bit_cast(float, u << 16); }
__device__ __forceinline__ float bfhi(unsigned u) { return __builtin_bit_cast(float, u & 0xffff0000u); }

__device__ __forceinline__ bf16x8 pack8(float4 a, float4 b) {
    bf16x8 r;
    r[0]=(short)f2bf(a.x); r[1]=(short)f2bf(a.y); r[2]=(short)f2bf(a.z); r[3]=(short)f2bf(a.w);
    r[4]=(short)f2bf(b.x); r[5]=(short)f2bf(b.y); r[6]=(short)f2bf(b.z); r[7]=(short)f2bf(b.w);
    return r;
}

// ---------------------------------------------------------------------------
// Edge logits via bf16 MFMA: C = Z Z^T + bias. 64x64 tile / 256-block.
// ---------------------------------------------------------------------------
__global__ __launch_bounds__(256) void edge_kernel(const unsigned short* __restrict__ zdb,
                                                   const float* __restrict__ bias,
                                                   float* __restrict__ out) {
    __shared__ float cstage[64][68];
    const int b  = blockIdx.z;
    const int tn = blockIdx.y * 64;
    const int tk = blockIdx.x * 64;
    const unsigned short* zb = zdb + (size_t)b * NMX * MD;
    const int tid = threadIdx.x, wave = tid >> 6, lane = tid & 63;
    const int l15 = lane & 15, k8 = (lane >> 4) * 8;

    const unsigned short* ap = zb + (size_t)(tn + wave * 16 + l15) * MD + k8;
    bf16x8 af0 = *(const bf16x8*)ap;
    bf16x8 af1 = *(const bf16x8*)(ap + 32);

    f32x4 acc[4];
    #pragma unroll
    for (int ct = 0; ct < 4; ct++) acc[ct] = (f32x4){0.f, 0.f, 0.f, 0.f};
    const unsigned short* bp = zb + (size_t)(tk + l15) * MD + k8;
    #pragma unroll
    for (int ct = 0; ct < 4; ct++) {
        bf16x8 b0 = *(const bf16x8*)(bp + (size_t)ct * 16 * MD);
        bf16x8 b1 = *(const bf16x8*)(bp + (size_t)ct * 16 * MD + 32);
        acc[ct] = __builtin_amdgcn_mfma_f32_16x16x32_bf16(af0, b0, acc[ct], 0, 0, 0);
        acc[ct] = __builtin_amdgcn_mfma_f32_16x16x32_bf16(af1, b1, acc[ct], 0, 0, 0);
    }
    #pragma unroll
    for (int ct = 0; ct < 4; ct++)
        #pragma unroll
        for (int i = 0; i < 4; i++)
            cstage[wave * 16 + (lane >> 4) * 4 + i][ct * 16 + l15] = acc[ct][i];
    __syncthreads();
    const float bi = bias[0];
    #pragma unroll
    for (int it = 0; it < 4; it++) {
        int f = tid + it * 256;
        int row = f >> 4, c4 = (f & 15) * 4;
        float4 v = *(const float4*)&cstage[row][c4];
        v.x += bi; v.y += bi; v.z += bi; v.w += bi;
        *(float4*)(out + ((size_t)b * NMX + tn + row) * NMX + tk + c4) = v;
    }
}

// ---------------------------------------------------------------------------
// Merged converters
// ---------------------------------------------------------------------------
__global__ __launch_bounds__(256) void cvt2_kernel(const float* __restrict__ a,
                                                   unsigned short* __restrict__ da, int n4a,
                                                   const float* __restrict__ b,
                                                   unsigned short* __restrict__ db, int n4b) {
    int i = blockIdx.x * 256 + threadIdx.x;
    if (i < n4a) {
        float4 v = *(const float4*)(a + (size_t)i * 4);
        ushort4 o = {f2bf(v.x), f2bf(v.y), f2bf(v.z), f2bf(v.w)};
        *(ushort4*)(da + (size_t)i * 4) = o;
    } else if (i < n4a + n4b) {
        int k = i - n4a;
        float4 v = *(const float4*)(b + (size_t)k * 4);
        ushort4 o = {f2bf(v.x), f2bf(v.y), f2bf(v.z), f2bf(v.w)};
        *(ushort4*)(db + (size_t)k * 4) = o;
    }
}

__global__ __launch_bounds__(256) void tcvt_all_kernel(const float* __restrict__ W_in,
                                                       const float* __restrict__ W_msg,
                                                       const float* __restrict__ W_upd,
                                                       unsigned short* __restrict__ wt_in,
                                                       unsigned short* __restrict__ wt_msg,
                                                       unsigned short* __restrict__ wt_upd) {
    const int y = blockIdx.y;
    const float* src; unsigned short* dst; int K;
    if (y == 0)        { src = W_in;                      dst = wt_in;                       K = MD; }
    else if (y <= RR)  { int r = y - 1;     src = W_msg + (size_t)r * HD * HD; dst = wt_msg + (size_t)r * HD * HD; K = HD; }
    else               { int r = y - 1 - RR; src = W_upd + (size_t)r * HD * HD; dst = wt_upd + (size_t)r * HD * HD; K = HD; }
    int i = blockIdx.x * 256 + threadIdx.x;
    if (i >= K * HD) return;
    int k = i / HD, h = i % HD;
    dst[(size_t)h * K + k] = f2bf(src[i]);
}

// ---------------------------------------------------------------------------
// Fused MLP (two MFMA stages), flat [n][K] layouts (R8 version).
// MODE 0: no addin, write state + msg.  MODE 1: +state_old, write state + msg.
// MODE 2: +state_old, node_out = state_new @ Wout + bout (no state write).
// ---------------------------------------------------------------------------
template <int K1, int MODE>
__global__ __launch_bounds__(256) void fused_kernel(
    const unsigned short* __restrict__ in,
    const unsigned short* __restrict__ Wt1,
    const float* __restrict__ b1,
    float* __restrict__ state,
    const unsigned short* __restrict__ Wt2,
    const float* __restrict__ b2,
    unsigned short* __restrict__ msgb,
    const float* __restrict__ Wout,
    const float* __restrict__ bout,
    float* __restrict__ node_out,
    int nrows)
{
    constexpr int KC1 = K1 / 32;
    __shared__ float cstage[64][132];
    __shared__ float sWout[MODE == 2 ? HD * FD : 1];
    const int tid = threadIdx.x, wave = tid >> 6, lane = tid & 63;
    const int l15 = lane & 15, k8 = (lane >> 4) * 8;
    const int rbase = blockIdx.x * 64;

    if constexpr (MODE == 2)
        for (int i = tid; i < HD * FD; i += 256) sWout[i] = Wout[i];

    // ---- stage 1 MFMA ----
    int rclamp = min(rbase + wave * 16 + l15, nrows - 1);
    bf16x8 af[KC1];
    #pragma unroll
    for (int c = 0; c < KC1; c++)
        af[c] = *(const bf16x8*)(in + (size_t)rclamp * K1 + (size_t)c * 32 + k8);
    f32x4 acc[8];
    #pragma unroll
    for (int ct = 0; ct < 8; ct++) acc[ct] = (f32x4){0.f, 0.f, 0.f, 0.f};
    const unsigned short* bp = Wt1 + (size_t)l15 * K1 + k8;
    #pragma unroll
    for (int ct = 0; ct < 8; ct++)
        #pragma unroll
        for (int c = 0; c < KC1; c++) {
            bf16x8 bf = *(const bf16x8*)(bp + (size_t)ct * 16 * K1 + c * 32);
            acc[ct] = __builtin_amdgcn_mfma_f32_16x16x32_bf16(af[c], bf, acc[ct], 0, 0, 0);
        }
    #pragma unroll
    for (int ct = 0; ct < 8; ct++)
        #pragma unroll
        for (int i = 0; i < 4; i++)
            cstage[wave * 16 + (lane >> 4) * 4 + i][ct * 16 + l15] = acc[ct][i];
    __syncthreads();

    // ---- epilogue 1: bias+relu (+state_old) -> state_new ----
    #pragma unroll
    for (int it = 0; it < 8; it++) {
        int f = tid + it * 256;
        int row = f >> 5, c4 = (f & 31) * 4;
        int grow = rbase + row;
        if (grow < nrows) {
            float4 v = *(const float4*)&cstage[row][c4];
            float4 bb = *(const float4*)(b1 + c4);
            v.x = fmaxf(v.x + bb.x, 0.f);
            v.y = fmaxf(v.y + bb.y, 0.f);
            v.z = fmaxf(v.z + bb.z, 0.f);
            v.w = fmaxf(v.w + bb.w, 0.f);
            if constexpr (MODE >= 1) {
                float4 so = *(const float4*)(state + (size_t)grow * HD + c4);
                v.x += so.x; v.y += so.y; v.z += so.z; v.w += so.w;
            }
            if constexpr (MODE <= 1)
                *(float4*)(state + (size_t)grow * HD + c4) = v;
            *(float4*)&cstage[row][c4] = v;
        }
    }
    __syncthreads();

    if constexpr (MODE <= 1) {
        // ---- stage 2 MFMA: A-frags from updated cstage ----
        bf16x8 af2[4];
        #pragma unroll
        for (int c = 0; c < 4; c++) {
            float4 u0 = *(const float4*)&cstage[wave * 16 + l15][c * 32 + k8];
            float4 u1 = *(const float4*)&cstage[wave * 16 + l15][c * 32 + k8 + 4];
            af2[c] = pack8(u0, u1);
        }
        f32x4 acc2[8];
        #pragma unroll
        for (int ct = 0; ct < 8; ct++) acc2[ct] = (f32x4){0.f, 0.f, 0.f, 0.f};
        const unsigned short* bp2 = Wt2 + (size_t)l15 * HD + k8;
        #pragma unroll
        for (int ct = 0; ct < 8; ct++)
            #pragma unroll
            for (int c = 0; c < 4; c++) {
                bf16x8 bf = *(const bf16x8*)(bp2 + (size_t)ct * 16 * HD + c * 32);
                acc2[ct] = __builtin_amdgcn_mfma_f32_16x16x32_bf16(af2[c], bf, acc2[ct], 0, 0, 0);
            }
        __syncthreads();
        #pragma unroll
        for (int ct = 0; ct < 8; ct++)
            #pragma unroll
            for (int i = 0; i < 4; i++)
                cstage[wave * 16 + (lane >> 4) * 4 + i][ct * 16 + l15] = acc2[ct][i];
        __syncthreads();
        #pragma unroll
        for (int it = 0; it < 8; it++) {
            int f = tid + it * 256;
            int row = f >> 5, c4 = (f & 31) * 4;
            int grow = rbase + row;
            if (grow < nrows) {
                float4 v = *(const float4*)&cstage[row][c4];
                float4 bb = *(const float4*)(b2 + c4);
                v.x = fmaxf(v.x + bb.x, 0.f);
                v.y = fmaxf(v.y + bb.y, 0.f);
                v.z = fmaxf(v.z + bb.z, 0.f);
                v.w = fmaxf(v.w + bb.w, 0.f);
                ushort4 o = {f2bf(v.x), f2bf(v.y), f2bf(v.z), f2bf(v.w)};
                *(ushort4*)(msgb + (size_t)grow * HD + c4) = o;
            }
        }
    } else {
        // ---- out projection: 64 rows x 7 cols, strided over 256 threads ----
        for (int i = tid; i < 64 * FD; i += 256) {
            int row = i / FD, ff = i - row * FD;
            int grow = rbase + row;
            if (grow < nrows) {
                float a = bout[ff];
                #pragma unroll 8
                for (int k = 0; k < HD; k++)
                    a += cstage[row][k] * sWout[k * FD + ff];
                node_out[(size_t)grow * FD + ff] = a;
            }
        }
    }
}

// ---------------------------------------------------------------------------
// CSR build via 2-phase MSD bucket sort — LDS atomics only.
// ex[] folded: ex(idx) = incl[idx] - bh[idx] + bsum[idx>>8].
// ---------------------------------------------------------------------------
__global__ __launch_bounds__(256) void p1c_kernel(const int* __restrict__ dst,
                                                  int* __restrict__ bh) {
    __shared__ int h[NH];
    const int b = blockIdx.x;
    for (int i = threadIdx.x; i < NH; i += 256) h[i] = 0;
    __syncthreads();
    const int e0 = b * BE;
    for (int i = threadIdx.x; i < BE; i += 256) {
        int e = e0 + i;
        if (e < EE) atomicAdd(&h[dst[e] >> 8], 1);
    }
    __syncthreads();
    for (int i = threadIdx.x; i < NH; i += 256) bh[i * NBL + b] = h[i];
}

__global__ __launch_bounds__(256) void scan1_kernel(const int* __restrict__ in,
                                                    int* __restrict__ incl,
                                                    int* __restrict__ bsum, int n) {
    __shared__ int s[256];
    int i = blockIdx.x * 256 + threadIdx.x;
    int t = threadIdx.x;
    s[t] = (i < n) ? in[i] : 0;
    __syncthreads();
    #pragma unroll
    for (int off = 1; off < 256; off <<= 1) {
        int x = (t >= off) ? s[t - off] : 0;
        __syncthreads();
        s[t] += x;
        __syncthreads();
    }
    if (i < n) incl[i] = s[t];
    if (t == 255) bsum[blockIdx.x] = s[255];
}

__global__ __launch_bounds__(256) void scan2_kernel(int* __restrict__ bsum, int nb) {
    __shared__ int s[256];
    int t = threadIdx.x;
    int orig = (t < nb) ? bsum[t] : 0;
    s[t] = orig;
    __syncthreads();
    #pragma unroll
    for (int off = 1; off < 256; off <<= 1) {
        int x = (t >= off) ? s[t - off] : 0;
        __syncthreads();
        s[t] += x;
        __syncthreads();
    }
    if (t < nb) bsum[t] = s[t] - orig;
}

__device__ __forceinline__ int ex_at(const int* bh, const int* incl,
                                     const int* bsum, int idx) {
    return incl[idx] - bh[idx] + bsum[idx >> 8];
}

__global__ __launch_bounds__(256) void p1s_kernel(const int* __restrict__ src,
                                                  const int* __restrict__ dst,
                                                  const int* __restrict__ bh,
                                                  const int* __restrict__ incl,
                                                  const int* __restrict__ bsum,
                                                  int2* __restrict__ sorted) {
    __shared__ int cur[NH];
    const int b = blockIdx.x;
    for (int i = threadIdx.x; i < NH; i += 256)
        cur[i] = ex_at(bh, incl, bsum, i * NBL + b);
    __syncthreads();
    const int e0 = b * BE;
    for (int i = threadIdx.x; i < BE; i += 256) {
        int e = e0 + i;
        if (e < EE) {
            int d = dst[e];
            int pos = atomicAdd(&cur[d >> 8], 1);
            sorted[pos] = make_int2(d, src[e]);
        }
    }
}

__global__ __launch_bounds__(256) void p2_kernel(const int2* __restrict__ sorted,
                                                 const int* __restrict__ bh,
                                                 const int* __restrict__ incl,
                                                 const int* __restrict__ bsum,
                                                 int* __restrict__ row_ptr,
                                                 int* __restrict__ colsrc) {
    __shared__ int hist[256];
    __shared__ int scanb[256];
    __shared__ int cur[256];
    const int h = blockIdx.x;
    const int t = threadIdx.x;
    const int base = ex_at(bh, incl, bsum, h * NBL);
    const int endp = (h == NH - 1) ? EE : ex_at(bh, incl, bsum, (h + 1) * NBL);
    const int cnt  = endp - base;
    hist[t] = 0;
    __syncthreads();
    for (int i = t; i < cnt; i += 256)
        atomicAdd(&hist[sorted[base + i].x & 255], 1);
    __syncthreads();
    scanb[t] = hist[t];
    __syncthreads();
    #pragma unroll
    for (int off = 1; off < 256; off <<= 1) {
        int x = (t >= off) ? scanb[t - off] : 0;
        __syncthreads();
        scanb[t] += x;
        __syncthreads();
    }
    int excl = scanb[t] - hist[t];
    cur[t] = excl;
    int v = h * 256 + t;
    if (v < NN) row_ptr[v] = base + excl;
    if (h == NH - 1 && t == 0) row_ptr[NN] = EE;
    __syncthreads();
    for (int i = t; i < cnt; i += 256) {
        int2 pr = sorted[base + i];
        int pos = base + atomicAdd(&cur[pr.x & 255], 1);
        colsrc[pos] = pr.y;
    }
}

// ---------------------------------------------------------------------------
// Gather v6: wave-per-node, 16-edge main loop (4 independent dwordx4 chains
// per lane slot -> ~4KB in flight per wave). Flat [node][16 u32] rows.
// Lane: e = lane>>4 (4 edge slots), q = lane&15 (16B quad).
// ---------------------------------------------------------------------------
__global__ __launch_bounds__(256) void gather_kernel(const int* __restrict__ rp,
                                                     const int* __restrict__ colsrc,
                                                     const u32x4* __restrict__ msg4,
                                                     u32x4* __restrict__ agg4) {
    int v = blockIdx.x * 4 + (threadIdx.x >> 6);
    if (v >= NN) return;
    const int lane = threadIdx.x & 63;
    const int e = lane >> 4, q = lane & 15;
    const int beg = rp[v], end = rp[v + 1];
    float a[8];
    #pragma unroll
    for (int i = 0; i < 8; i++) a[i] = 0.f;

    int j = beg;
    for (; j + 15 < end; j += 16) {
        int c0 = colsrc[j + e];
        int c1 = colsrc[j + 4 + e];
        int c2 = colsrc[j + 8 + e];
        int c3 = colsrc[j + 12 + e];
        u32x4 u0 = msg4[(size_t)c0 * 16 + q];
        u32x4 u1 = msg4[(size_t)c1 * 16 + q];
        u32x4 u2 = msg4[(size_t)c2 * 16 + q];
        u32x4 u3 = msg4[(size_t)c3 * 16 + q];
        a[0] += bflo(u0.x); a[1] += bfhi(u0.x);
        a[2] += bflo(u0.y); a[3] += bfhi(u0.y);
        a[4] += bflo(u0.z); a[5] += bfhi(u0.z);
        a[6] += bflo(u0.w); a[7] += bfhi(u0.w);
        a[0] += bflo(u1.x); a[1] += bfhi(u1.x);
        a[2] += bflo(u1.y); a[3] += bfhi(u1.y);
        a[4] += bflo(u1.z); a[5] += bfhi(u1.z);
        a[6] += bflo(u1.w); a[7] += bfhi(u1.w);
        a[0] += bflo(u2.x); a[1] += bfhi(u2.x);
        a[2] += bflo(u2.y); a[3] += bfhi(u2.y);
        a[4] += bflo(u2.z); a[5] += bfhi(u2.z);
        a[6] += bflo(u2.w); a[7] += bfhi(u2.w);
        a[0] += bflo(u3.x); a[1] += bfhi(u3.x);
        a[2] += bflo(u3.y); a[3] += bfhi(u3.y);
        a[4] += bflo(u3.z); a[5] += bfhi(u3.z);
        a[6] += bflo(u3.w); a[7] += bfhi(u3.w);
    }
    for (; j < end; j += 4) {
        if (j + e < end) {
            u32x4 u = msg4[(size_t)colsrc[j + e] * 16 + q];
            a[0] += bflo(u.x); a[1] += bfhi(u.x);
            a[2] += bflo(u.y); a[3] += bfhi(u.y);
            a[4] += bflo(u.z); a[5] += bfhi(u.z);
            a[6] += bflo(u.w); a[7] += bfhi(u.w);
        }
    }
    // reduce across the 4 edge-groups (lanes q, q+16, q+32, q+48)
    #pragma unroll
    for (int i = 0; i < 8; i++) {
        a[i] += __shfl_xor(a[i], 16);
        a[i] += __shfl_xor(a[i], 32);
    }
    if (lane < 16) {
        u32x4 o;
        o.x = (unsigned)f2bf(a[0]) | ((unsigned)f2bf(a[1]) << 16);
        o.y = (unsigned)f2bf(a[2]) | ((unsigned)f2bf(a[3]) << 16);
        o.z = (unsigned)f2bf(a[4]) | ((unsigned)f2bf(a[5]) << 16);
        o.w = (unsigned)f2bf(a[6]) | ((unsigned)f2bf(a[7]) << 16);
        __builtin_nontemporal_store(o, &agg4[(size_t)v * 16 + q]);
    }
}

extern "C" void kernel_launch(void* const* d_in, const int* in_sizes, int n_in,
                              void* d_out, int out_size, void* d_ws, size_t ws_size,
                              hipStream_t stream) {
    const float* z          = (const float*)d_in[0];
    const int*   edge_index = (const int*)  d_in[1];
    const float* z_dense    = (const float*)d_in[2];
    const float* bias       = (const float*)d_in[3];
    const float* W_in       = (const float*)d_in[4];
    const float* b_in       = (const float*)d_in[5];
    const float* W_msg      = (const float*)d_in[6];
    const float* b_msg      = (const float*)d_in[7];
    const float* W_upd      = (const float*)d_in[8];
    const float* b_upd      = (const float*)d_in[9];
    const float* W_out      = (const float*)d_in[10];
    const float* b_out      = (const float*)d_in[11];

    float* out      = (float*)d_out;
    float* edge_out = out;
    float* node_out = out + (size_t)BG * NMX * NMX;

    // ---- workspace (flat layouts) ----
    char* p = (char*)d_ws;
    float* state = (float*)p;                     p += (size_t)NN * HD * 4;
    unsigned short* msgb   = (unsigned short*)p;  p += (size_t)NN * HD * 2;
    unsigned short* aggb   = (unsigned short*)p;  p += (size_t)NN * HD * 2;
    unsigned short* zb     = (unsigned short*)p;  p += (size_t)NN * MD * 2;
    unsigned short* zdb    = (unsigned short*)p;  p += (size_t)BG * NMX * MD * 2;
    unsigned short* wt_in  = (unsigned short*)p;  p += (size_t)HD * MD * 2;
    unsigned short* wt_msg = (unsigned short*)p;  p += (size_t)RR * HD * HD * 2;
    unsigned short* wt_upd = (unsigned short*)p;  p += (size_t)RR * HD * HD * 2;
    int*  bh      = (int*)p;                      p += (size_t)NS * 4;
    int*  incl    = (int*)p;                      p += (size_t)NS * 4;
    int*  row_ptr = (int*)p;                      p += (size_t)(NN + 1) * 4;
    int*  colsrc  = (int*)p;                      p += (size_t)EE * 4;
    int2* sorted  = (int2*)p;                     p += (size_t)EE * 8;
    int*  bsum    = (int*)p;

    const int* src = edge_index;
    const int* dst = edge_index + EE;

    // ---- conversions (merged) ----
    const int n4zd = BG * NMX * MD / 4;
    const int n4z  = NN * MD / 4;
    cvt2_kernel<<<(n4zd + n4z + 255) / 256, 256, 0, stream>>>(
        z_dense, zdb, n4zd, z, zb, n4z);

    // ---- edge path ----
    dim3 eg(NMX / 64, NMX / 64, BG);
    edge_kernel<<<eg, 256, 0, stream>>>(zdb, bias, edge_out);

    tcvt_all_kernel<<<dim3((HD * HD + 255) / 256, 1 + 2 * RR), 256, 0, stream>>>(
        W_in, W_msg, W_upd, wt_in, wt_msg, wt_upd);

    // ---- CSR build: MSD bucket sort (LDS atomics only, 5 dispatches) ----
    p1c_kernel<<<NBL, 256, 0, stream>>>(dst, bh);
    scan1_kernel<<<NSB, 256, 0, stream>>>(bh, incl, bsum, NS);
    scan2_kernel<<<1, 256, 0, stream>>>(bsum, NSB);
    p1s_kernel<<<NBL, 256, 0, stream>>>(src, dst, bh, incl, bsum, sorted);
    p2_kernel<<<NH, 256, 0, stream>>>(sorted, bh, incl, bsum, row_ptr, colsrc);

    // ---- node pipeline ----
    const int MG = (NN + 63) / 64;
    const int GG = (NN + 3) / 4;

    fused_kernel<MD, 0><<<MG, 256, 0, stream>>>(
        zb, wt_in, b_in, state,
        wt_msg, b_msg, msgb, nullptr, nullptr, nullptr, NN);

    for (int r = 0; r < RR - 1; r++) {
        gather_kernel<<<GG, 256, 0, stream>>>(row_ptr, colsrc,
                                              (const u32x4*)msgb, (u32x4*)aggb);
        fused_kernel<HD, 1><<<MG, 256, 0, stream>>>(
            aggb, wt_upd + (size_t)r * HD * HD, b_upd + (size_t)r * HD, state,
            wt_msg + (size_t)(r + 1) * HD * HD, b_msg + (size_t)(r + 1) * HD,
            msgb, nullptr, nullptr, nullptr, NN);
    }
    gather_kernel<<<GG, 256, 0, stream>>>(row_ptr, colsrc,
                                          (const u32x4*)msgb, (u32x4*)aggb);
    fused_kernel<HD, 2><<<MG, 256, 0, stream>>>(
        aggb, wt_upd + (size_t)(RR - 1) * HD * HD, b_upd + (size_t)(RR - 1) * HD, state,
        nullptr, nullptr, nullptr, W_out, b_out, node_out, NN);
}